// Round 1
// baseline (764.897 us; speedup 1.0000x reference)
//
#include <hip/hip_runtime.h>

#define ROWS 256
#define COLS 256
#define NP (ROWS*COLS)
#define BATCH 32

// f32 weight workspace layout (element offsets in d_ws)
#define WX_OFF 0      // 9 x 64
#define WH_OFF 576    // 16 x 64
#define B_OFF  1600   // 64
#define WO_OFF 1664   // 16 x 9
#define BO_OFF 1808   // 9
#define FLAG_OFF 1824 // int flag: 1 = inputs are f32, 0 = bf16

// d_out element offsets
#define OUT_DYN 0
#define OUT_LAT 2097152
#define OUT_H   18874368
#define OUT_C   52428800

using u16 = unsigned short;
using u32 = unsigned int;

__device__ __forceinline__ float bf2f(u16 v){ return __uint_as_float(((u32)v) << 16); }
__device__ __forceinline__ u16 f2bf(float f){
    u32 u = __float_as_uint(f);
    return (u16)((u + 0x7fffu + ((u >> 16) & 1u)) >> 16);   // RNE
}
__device__ __forceinline__ float rcpf_(float x){ return __builtin_amdgcn_rcpf(x); }
__device__ __forceinline__ float sigm(float x){ return rcpf_(1.f + __expf(-x)); }
__device__ __forceinline__ float tanh_(float x){ return 1.f - 2.f * rcpf_(1.f + __expf(2.f * x)); }
__device__ __forceinline__ void unpack2(u32 u, float& a, float& b){
    a = __uint_as_float(u << 16);
    b = __uint_as_float(u & 0xffff0000u);
}
__device__ __forceinline__ u32 pk2(float a, float b){
    return (u32)f2bf(a) | ((u32)f2bf(b) << 16);
}

// Single-block prep: detect input dtype from Wx bit patterns, then convert all
// weights to f32 in d_ws under the detected interpretation.
__global__ void prep_weights(const void* __restrict__ Wx, const void* __restrict__ Wh,
                             const void* __restrict__ b,  const void* __restrict__ Wo,
                             const void* __restrict__ bo, float* __restrict__ ws){
    __shared__ int sflag;
    const int t = threadIdx.x;
    if (t == 0) sflag = 0;
    __syncthreads();
    float v = bf2f(((const u16*)Wx)[t]);
    if (!(fabsf(v) < 64.0f)) atomicOr(&sflag, 1);
    __syncthreads();
    const int f32in = sflag;

    for (int i = t; i < 576;  i += 256) ws[WX_OFF+i] = f32in ? ((const float*)Wx)[i] : bf2f(((const u16*)Wx)[i]);
    for (int i = t; i < 1024; i += 256) ws[WH_OFF+i] = f32in ? ((const float*)Wh)[i] : bf2f(((const u16*)Wh)[i]);
    for (int i = t; i < 64;   i += 256) ws[B_OFF+i]  = f32in ? ((const float*)b)[i]  : bf2f(((const u16*)b)[i]);
    for (int i = t; i < 144;  i += 256) ws[WO_OFF+i] = f32in ? ((const float*)Wo)[i] : bf2f(((const u16*)Wo)[i]);
    for (int i = t; i < 9;    i += 256) ws[BO_OFF+i] = f32in ? ((const float*)bo)[i] : bf2f(((const u16*)bo)[i]);
    if (t == 0) ((int*)ws)[FLAG_OFF] = f32in;
}

// One thread per (batch, cell). Block = one grid row (256 cols) of one batch.
// XCD-swizzled so neighbor rows (which share lat_out halo rows) land on the
// same XCD's L2. LDS transposed to [d][3][col] so gather + stage are
// bank-conflict-free. Gate matmul chunked 4x16 to cap live VGPRs (~16 accs
// instead of 64) for higher occupancy -> more outstanding HBM requests.
__global__ __launch_bounds__(256) void lstm_step(
    const void* __restrict__ dyn_in,
    const void* __restrict__ lat_in,   // fallback at boundary cells only
    const void* __restrict__ lat_out,
    const void* __restrict__ h_in,
    const void* __restrict__ c_in,
    const float* __restrict__ W,       // f32 weights + flag in d_ws
    void* __restrict__ out)
{
    // Bijective XCD swizzle: original consecutive wg ids round-robin over the
    // 8 XCDs; remap so each XCD owns a contiguous run of (batch,row) work.
    const int wg = blockIdx.y * gridDim.x + blockIdx.x;        // 0..8191
    const int sw = (wg & 7) * ((ROWS * BATCH) / 8) + (wg >> 3); // 8192 % 8 == 0
    const int r   = sw & (ROWS - 1);
    const int bb  = sw >> 8;
    const int col = threadIdx.x;
    const long base = (long)bb * NP + (long)r * COLS + col;
    const int f32in = ((const int*)W)[FLAG_OFF];   // block-uniform

    // Transposed halo stage: [direction][haloRow][col], f32 always (24 KB).
    // Gather reads lds[d][rr][nc] with consecutive nc across lanes -> 2
    // lanes/bank (free). Stage writes lds[d][rr][col] likewise conflict-free.
    __shared__ float lds[8][3][COLS];

    const int drr[8] = {-1,-1,-1, 0, 0, 1, 1, 1};
    const int dcc[8] = {-1, 0, 1,-1, 1,-1, 0, 1};

    // ---- stage lat_out rows r-1..r+1 (each thread owns its column's 8 vals) ----
    if (f32in){
        #pragma unroll
        for (int rr = 0; rr < 3; rr++){
            int row = r + rr - 1;
            if (row >= 0 && row < ROWS){
                const float4* s = (const float4*)((const float*)lat_out + ((long)bb * NP + (long)row * COLS) * 8);
                float4 a = s[2*col], b4 = s[2*col+1];
                lds[0][rr][col] = a.x;  lds[1][rr][col] = a.y;
                lds[2][rr][col] = a.z;  lds[3][rr][col] = a.w;
                lds[4][rr][col] = b4.x; lds[5][rr][col] = b4.y;
                lds[6][rr][col] = b4.z; lds[7][rr][col] = b4.w;
            }
        }
    } else {
        #pragma unroll
        for (int rr = 0; rr < 3; rr++){
            int row = r + rr - 1;
            if (row >= 0 && row < ROWS){
                const uint4* s = (const uint4*)((const u16*)lat_out + ((long)bb * NP + (long)row * COLS) * 8);
                uint4 a = s[col];
                float e0,e1,e2,e3,e4,e5,e6,e7;
                unpack2(a.x, e0, e1); unpack2(a.y, e2, e3);
                unpack2(a.z, e4, e5); unpack2(a.w, e6, e7);
                lds[0][rr][col] = e0; lds[1][rr][col] = e1;
                lds[2][rr][col] = e2; lds[3][rr][col] = e3;
                lds[4][rr][col] = e4; lds[5][rr][col] = e5;
                lds[6][rr][col] = e6; lds[7][rr][col] = e7;
            }
        }
    }

    // ---- issue dyn/h loads before the barrier to overlap their latency ----
    float x[9], hv[16];
    if (f32in){
        x[0] = ((const float*)dyn_in)[base];
        const float4* hp = (const float4*)h_in + base * 4;
        #pragma unroll
        for (int qq = 0; qq < 4; qq++){
            float4 hq = hp[qq];
            hv[4*qq+0]=hq.x; hv[4*qq+1]=hq.y; hv[4*qq+2]=hq.z; hv[4*qq+3]=hq.w;
        }
    } else {
        x[0] = bf2f(((const u16*)dyn_in)[base]);
        const uint4* hp = (const uint4*)h_in + base * 2;
        uint4 h0 = hp[0], h1 = hp[1];
        unpack2(h0.x, hv[0], hv[1]);   unpack2(h0.y, hv[2], hv[3]);
        unpack2(h0.z, hv[4], hv[5]);   unpack2(h0.w, hv[6], hv[7]);
        unpack2(h1.x, hv[8], hv[9]);   unpack2(h1.y, hv[10], hv[11]);
        unpack2(h1.z, hv[12], hv[13]); unpack2(h1.w, hv[14], hv[15]);
    }

    __syncthreads();

    // ---- gather laterals (conflict-free LDS reads; global fallback at edges) ----
    #pragma unroll
    for (int d = 0; d < 8; d++){
        int nr = r + drr[d], nc = col + dcc[d];
        if (nr >= 0 && nr < ROWS && nc >= 0 && nc < COLS){
            x[1 + d] = lds[d][drr[d] + 1][nc];
        } else {
            x[1 + d] = f32in ? ((const float*)lat_in)[base * 8 + d]
                             : bf2f(((const u16*)lat_in)[base * 8 + d]);
        }
    }

    // ---- gates + pointwise + Wo, chunked over k in groups of 4 ----
    float oacc[9];
    #pragma unroll
    for (int t = 0; t < 9; t++) oacc[t] = W[BO_OFF + t];

    #pragma unroll 1
    for (int q = 0; q < 4; q++){
        const int cb = 4 * q;

        // c chunk load first: ~400 FMAs below cover its latency
        float cva, cvb, cvc, cvd;
        if (f32in){
            float4 cq = ((const float4*)c_in)[base * 4 + q];
            cva = cq.x; cvb = cq.y; cvc = cq.z; cvd = cq.w;
        } else {
            uint2 cu = ((const uint2*)c_in)[base * 4 + q];
            unpack2(cu.x, cva, cvb); unpack2(cu.y, cvc, cvd);
        }

        float ai[4], af[4], ag[4], ao[4];
        #pragma unroll
        for (int kk = 0; kk < 4; kk++){
            ai[kk] = W[B_OFF + cb + kk];
            af[kk] = W[B_OFF + 16 + cb + kk];
            ag[kk] = W[B_OFF + 32 + cb + kk];
            ao[kk] = W[B_OFF + 48 + cb + kk];
        }
        #pragma unroll
        for (int m = 0; m < 9; m++){
            const float xm = x[m];
            const float* wb = W + WX_OFF + m * 64 + cb;
            #pragma unroll
            for (int kk = 0; kk < 4; kk++){
                ai[kk] = fmaf(xm, wb[kk],      ai[kk]);
                af[kk] = fmaf(xm, wb[16 + kk], af[kk]);
                ag[kk] = fmaf(xm, wb[32 + kk], ag[kk]);
                ao[kk] = fmaf(xm, wb[48 + kk], ao[kk]);
            }
        }
        #pragma unroll
        for (int m = 0; m < 16; m++){
            const float hm = hv[m];
            const float* wb = W + WH_OFF + m * 64 + cb;
            #pragma unroll
            for (int kk = 0; kk < 4; kk++){
                ai[kk] = fmaf(hm, wb[kk],      ai[kk]);
                af[kk] = fmaf(hm, wb[16 + kk], af[kk]);
                ag[kk] = fmaf(hm, wb[32 + kk], ag[kk]);
                ao[kk] = fmaf(hm, wb[48 + kk], ao[kk]);
            }
        }

        const float cvv[4] = {cva, cvb, cvc, cvd};
        float hn4[4], cn4[4];
        #pragma unroll
        for (int kk = 0; kk < 4; kk++){
            float ig = sigm(ai[kk]);
            float fg = sigm(af[kk]);
            float gg = tanh_(ag[kk]);
            float og = sigm(ao[kk]);
            float cc = fmaf(fg, cvv[kk], ig * gg);
            float hh = og * tanh_(cc);
            cn4[kk] = cc; hn4[kk] = hh;
            const float* wo = W + WO_OFF + (cb + kk) * 9;
            #pragma unroll
            for (int t = 0; t < 9; t++) oacc[t] = fmaf(hh, wo[t], oacc[t]);
        }

        // store this h/c chunk immediately (frees the registers)
        if (f32in){
            float* of = (float*)out;
            ((float4*)(of + OUT_H))[base * 4 + q] = make_float4(hn4[0], hn4[1], hn4[2], hn4[3]);
            ((float4*)(of + OUT_C))[base * 4 + q] = make_float4(cn4[0], cn4[1], cn4[2], cn4[3]);
        } else {
            u16* ob = (u16*)out;
            ((uint2*)(ob + OUT_H))[base * 4 + q] = make_uint2(pk2(hn4[0], hn4[1]), pk2(hn4[2], hn4[3]));
            ((uint2*)(ob + OUT_C))[base * 4 + q] = make_uint2(pk2(cn4[0], cn4[1]), pk2(cn4[2], cn4[3]));
        }
    }

    // ---- epilogue: dyn + lateral outputs ----
    float dynout = tanh_(oacc[0]);
    float ov[8];
    #pragma unroll
    for (int t = 0; t < 8; t++) ov[t] = tanh_(oacc[1 + t]);

    if (f32in){
        float* of = (float*)out;
        of[OUT_DYN + base] = dynout;
        float4* lp = (float4*)(of + OUT_LAT) + base * 2;
        lp[0] = make_float4(ov[0], ov[1], ov[2], ov[3]);
        lp[1] = make_float4(ov[4], ov[5], ov[6], ov[7]);
    } else {
        u16* ob = (u16*)out;
        ob[OUT_DYN + base] = f2bf(dynout);
        *((uint4*)(ob + OUT_LAT) + base) =
            make_uint4(pk2(ov[0], ov[1]), pk2(ov[2], ov[3]), pk2(ov[4], ov[5]), pk2(ov[6], ov[7]));
    }
}

extern "C" void kernel_launch(void* const* d_in, const int* in_sizes, int n_in,
                              void* d_out, int out_size, void* d_ws, size_t ws_size,
                              hipStream_t stream){
    const void* dyn  = d_in[0];
    const void* lin  = d_in[1];
    const void* lout = d_in[2];
    const void* h    = d_in[3];
    const void* c    = d_in[4];
    const void* Wx   = d_in[5];
    const void* Wh   = d_in[6];
    const void* b    = d_in[7];
    const void* Wo   = d_in[8];
    const void* bo   = d_in[9];
    float* ws = (float*)d_ws;

    hipLaunchKernelGGL(prep_weights, dim3(1), dim3(256), 0, stream, Wx, Wh, b, Wo, bo, ws);
    hipLaunchKernelGGL(lstm_step, dim3(ROWS, BATCH), dim3(256), 0, stream,
                       dyn, lin, lout, h, c, ws, d_out);
}